// Round 3
// baseline (300.055 us; speedup 1.0000x reference)
//
#include <hip/hip_runtime.h>
#include <hip/hip_bf16.h>

// Problem constants
#define BB 2
#define SS 2048
#define DD 1024
#define HH 16
#define HD 64
#define MM (BB*SS)   // 4096

typedef __attribute__((ext_vector_type(8))) short bf16x8;
typedef __attribute__((ext_vector_type(4))) float f32x4;

static __device__ inline unsigned short f2bf(float x) {
    unsigned int u = __float_as_uint(x);
    unsigned int r = (u + 0x7fffu + ((u >> 16) & 1u)) >> 16;
    return (unsigned short)r;
}

// packed f32x2 -> bf16x2 via v_cvt_pk_bf16_f32 (RNE, bit-identical to f2bf)
static __device__ inline unsigned pack2bf(float lo, float hi) {
    union { __hip_bfloat162 h; unsigned u; } c;
    c.h = __float22bfloat162_rn(make_float2(lo, hi));
    return c.u;
}

static __device__ inline f32x4 mfma16(bf16x8 a, bf16x8 b, f32x4 c) {
    return __builtin_amdgcn_mfma_f32_16x16x32_bf16(a, b, c, 0, 0, 0);
}

// raw v_exp_f32 (2^x)
static __device__ inline float fast_exp2(float x) {
    return __builtin_amdgcn_exp2f(x);
}

// async global->LDS 16B per lane: LDS dest = wave-uniform base + lane*16
typedef __attribute__((address_space(3))) unsigned int lds_u32;
typedef const __attribute__((address_space(1))) unsigned int glb_u32;
static __device__ inline void async_ld16(const void* g, void* l) {
    __builtin_amdgcn_global_load_lds((glb_u32*)g, (lds_u32*)l, 16, 0, 0);
}

// ---------------- fused prep: z<3 -> fp32->bf16 convert of q/k/v; z>=3 -> weight
// transpose+convert [R][C]fp32 -> [C][R]bf16.
struct PrepArgs {
    const float* csrc[3];
    unsigned short* cdst[3];
    const float* wsrc[4];
    unsigned short* wdst[4];
};
__global__ __launch_bounds__(256) void prep_inputs(PrepArgs args) {
    const int z = blockIdx.z;
    const int t = threadIdx.x;
    if (z < 3) {
        const float* in = args.csrc[z];
        unsigned short* out = args.cdst[z];
        int chunk = (blockIdx.y * 32 + blockIdx.x) * 4096;
#pragma unroll
        for (int r = 0; r < 4; r++) {
            int i = chunk + r * 1024 + t * 4;
            float4 v = *(const float4*)(in + i);
            uint2 o;
            o.x = pack2bf(v.x, v.y);
            o.y = pack2bf(v.z, v.w);
            *(uint2*)(out + i) = o;
        }
    } else {
        __shared__ float tile[32][33];
        const float* in = args.wsrc[z - 3];
        unsigned short* out = args.wdst[z - 3];
        int c0 = blockIdx.x * 32, r0 = blockIdx.y * 32;
        int x = t & 31, y0 = t >> 5;
        for (int yy = y0; yy < 32; yy += 8)
            tile[yy][x] = in[(size_t)(r0 + yy) * DD + c0 + x];
        __syncthreads();
        for (int yy = y0; yy < 32; yy += 8)
            out[(size_t)(c0 + yy) * DD + r0 + x] = f2bf(tile[x][yy]);
    }
}

struct QKVArgs {
    const unsigned short* A[3];
    const unsigned short* Bt[3];
    const float* bias[3];
    unsigned short* C[3];
};

// Q scale folds 1/sqrt(HD) AND log2(e) so flash can use exp2 directly.
#define QSCALE 0.1803368801111204f

// ---------------- QKV GEMM: 256x256 tile, BK=32, 4-deep LDS pipeline, 8 waves ------
// T3+T4: stage tile kt+3 while computing tile kt; tile-boundary wait = vmcnt(8)
// (2 tiles in flight, never 0 in main loop); raw s_barrier (no drain).
// T5: setprio(1) around the 32-MFMA cluster.
// T2-equivalent: 16B-granule XOR swizzle (slot ^= (row>>1)&3), applied BOTH sides
// (pre-swizzled global source + swizzled ds_read addr; LDS dest stays linear for
// global_load_lds) -> 16 l15-rows spread over all 8 bank-quads = 2-way (free).
#define NBUF 4
#define NT (DD / 32)   // 32 K-tiles

__global__ __launch_bounds__(512, 2) void gemm_qkv(QKVArgs args) {
    __shared__ alignas(16) unsigned short AS[NBUF][256 * 32];
    __shared__ alignas(16) unsigned short BS[NBUF][256 * 32];
    const int z = blockIdx.z;
    const float scale = (z == 0) ? QSCALE : 1.0f;
    const unsigned short* __restrict__ A = args.A[z];
    const unsigned short* __restrict__ Bt = args.Bt[z];
    const float* __restrict__ bias = args.bias[z];
    unsigned short* __restrict__ C = args.C[z];
    const int K = DD, N = DD;
    const int t = threadIdx.x;
    const int lane = t & 63, wave = t >> 6;
    const int quad = lane >> 4, l15 = lane & 15;
    const int wm = wave & 1, wn = wave >> 1;    // 2 M-waves x 4 N-waves
    const int m0 = blockIdx.y * 256, n0 = blockIdx.x * 256;

    // Staging geometry: per tile, each thread issues 4x global_load_lds(16B):
    // A rows 0..127 (c=0) / 128..255 (c=1), same for B. Each wave-call covers 16
    // rows of 64B. Source slot is pre-swizzled so linear LDS + swizzled read match.
    const int srow = wave * 16 + (lane >> 2);                 // 0..127
    const int sslot = (lane & 3) ^ ((lane >> 3) & 3);         // swizzled 16B slot
    const unsigned short* gA0 = A + (size_t)(m0 + srow) * K + sslot * 8;
    const unsigned short* gA1 = gA0 + (size_t)128 * K;
    const unsigned short* gB0 = Bt + (size_t)(n0 + srow) * K + sslot * 8;
    const unsigned short* gB1 = gB0 + (size_t)128 * K;
    const int rlo = wave * 512;            // LDS region (shorts): c=0
    const int rhi = wave * 512 + 4096;     // c=1 (rows 128..255)

    // ds_read swizzle: row R, k-slot quad -> slot quad ^ ((R>>1)&3); with
    // R = base16 + l15 this is quad ^ ((l15>>1)&3), independent of fragment idx.
    const int swzq = quad ^ ((l15 >> 1) & 3);

    auto stage = [&](int kt) {
        const int b = kt & (NBUF - 1);
        const size_t ko = (size_t)kt * 32;
        async_ld16(gA0 + ko, &AS[b][rlo]);
        async_ld16(gA1 + ko, &AS[b][rhi]);
        async_ld16(gB0 + ko, &BS[b][rlo]);
        async_ld16(gB1 + ko, &BS[b][rhi]);
    };

    // prologue: 3 tiles in flight (12 loads outstanding)
    stage(0); stage(1); stage(2);

    f32x4 acc[8][4];
#pragma unroll
    for (int i = 0; i < 8; i++)
#pragma unroll
        for (int j = 0; j < 4; j++) acc[i][j] = (f32x4){0.f, 0.f, 0.f, 0.f};

#pragma unroll 4
    for (int kt = 0; kt < NT; ++kt) {
        // Wait tile kt staged. Steady state: allow tiles kt+1,kt+2 (8 loads) in
        // flight. Tail iterations tighten the count (correctness must not rely
        // on timing).
        if (kt < NT - 2)       asm volatile("s_waitcnt vmcnt(8)" ::: "memory");
        else if (kt == NT - 2) asm volatile("s_waitcnt vmcnt(4)" ::: "memory");
        else                   asm volatile("s_waitcnt vmcnt(0)" ::: "memory");
        // Barrier BEFORE issuing stage(kt+3): guarantees every wave finished its
        // ds_reads of buf[(kt+3)&3] (= buf[(kt-1)&3], consumed last iteration).
        __builtin_amdgcn_s_barrier();
        if (kt + 3 < NT) stage(kt + 3);

        const unsigned short* Ab = AS[kt & (NBUF - 1)];
        const unsigned short* Bb = BS[kt & (NBUF - 1)];
        bf16x8 af[8], bfr[4];
#pragma unroll
        for (int i = 0; i < 8; i++)
            af[i] = *(const bf16x8*)&Ab[(wm * 128 + i * 16 + l15) * 32 + swzq * 8];
#pragma unroll
        for (int j = 0; j < 4; j++)
            bfr[j] = *(const bf16x8*)&Bb[(wn * 64 + j * 16 + l15) * 32 + swzq * 8];

        __builtin_amdgcn_s_setprio(1);
#pragma unroll
        for (int i = 0; i < 8; i++)
#pragma unroll
            for (int j = 0; j < 4; j++)
                acc[i][j] = mfma16(af[i], bfr[j], acc[i][j]);
        __builtin_amdgcn_s_setprio(0);
    }

    if (z == 2) {
        // write C^T into [B][N][S]: token m = b*SS+s, dim col -> dst[b][col][s]
#pragma unroll
        for (int j = 0; j < 4; j++) {
            int col = n0 + wn * 64 + j * 16 + l15;
            float bv = bias[col];
#pragma unroll
            for (int i = 0; i < 8; i++) {
                int rowb = m0 + wm * 128 + i * 16 + quad * 4;
                int b = rowb >> 11, s = rowb & (SS - 1);
                uint2 w;
                w.x = pack2bf(acc[i][j][0] + bv, acc[i][j][1] + bv);
                w.y = pack2bf(acc[i][j][2] + bv, acc[i][j][3] + bv);
                *(uint2*)(C + (size_t)b * DD * SS + (size_t)col * SS + s) = w;
            }
        }
    } else {
#pragma unroll
        for (int j = 0; j < 4; j++) {
            int col = n0 + wn * 64 + j * 16 + l15;
            float bv = bias[col];
#pragma unroll
            for (int i = 0; i < 8; i++) {
                int rowb = m0 + wm * 128 + i * 16 + quad * 4;
#pragma unroll
                for (int rr = 0; rr < 4; rr++) {
                    float v = (acc[i][j][rr] + bv) * scale;
                    C[(size_t)(rowb + rr) * N + col] = f2bf(v);
                }
            }
        }
    }
}

// ---------------- 128x64-tile GEMM for the output projection -----------------------
__global__ __launch_bounds__(256) void gemm_out(const unsigned short* __restrict__ A,
                                                const unsigned short* __restrict__ Bt,
                                                const float* __restrict__ bias,
                                                float* __restrict__ C) {
    __shared__ alignas(16) unsigned short As[128 * 32];
    __shared__ alignas(16) unsigned short Bs[64 * 32];
    const int t = threadIdx.x;
    const int lane = t & 63, wave = t >> 6;
    const int quad = lane >> 4, l15 = lane & 15;
    const int m0 = blockIdx.y * 128, n0 = blockIdx.x * 64;
    const int K = DD, N = DD;

    const unsigned short* gA = A + (size_t)(m0 + wave * 16 + (lane >> 2)) * K + (lane & 3) * 8;
    const unsigned short* gB = Bt + (size_t)(n0 + wave * 16 + (lane >> 2)) * K + (lane & 3) * 8;
    unsigned short* lA0 = &As[(wave * 16) * 32];
    unsigned short* lA1 = &As[(wave * 16 + 64) * 32];
    unsigned short* lB0 = &Bs[(wave * 16) * 32];

    f32x4 acc[2][4];
#pragma unroll
    for (int i = 0; i < 2; i++)
#pragma unroll
        for (int j = 0; j < 4; j++) acc[i][j] = (f32x4){0.f, 0.f, 0.f, 0.f};

    for (int k0 = 0; k0 < K; k0 += 32) {
        __syncthreads();
        async_ld16(gA + k0, lA0);
        async_ld16(gA + (size_t)64 * K + k0, lA1);
        async_ld16(gB + k0, lB0);
        __syncthreads();

        bf16x8 af[2], bfr[4];
#pragma unroll
        for (int i = 0; i < 2; i++)
            af[i] = *(const bf16x8*)&As[(wave * 32 + i * 16 + l15) * 32 + quad * 8];
#pragma unroll
        for (int j = 0; j < 4; j++)
            bfr[j] = *(const bf16x8*)&Bs[(j * 16 + l15) * 32 + quad * 8];
#pragma unroll
        for (int i = 0; i < 2; i++)
#pragma unroll
            for (int j = 0; j < 4; j++)
                acc[i][j] = mfma16(af[i], bfr[j], acc[i][j]);
    }

#pragma unroll
    for (int j = 0; j < 4; j++) {
        int col = n0 + j * 16 + l15;
        float bv = bias[col];
#pragma unroll
        for (int i = 0; i < 2; i++) {
            int rowb = m0 + wave * 32 + i * 16 + quad * 4;
#pragma unroll
            for (int rr = 0; rr < 4; rr++)
                C[(size_t)(rowb + rr) * N + col] = acc[i][j][rr] + bv;
        }
    }
}

// ---------------- flash attention v7: K-only LDS, V direct from L2 ------------------
// Round-2 change: rounds 0/1 showed occupancy doesn't move the needle — the LDS
// read port is the shared limiter (round-1: 256KB/CU/tile ≈ measured 60µs).
// Fix: (a) V fragments read directly from global Vt[B][D][S] (per-XCD working
// set 4 heads x 512KB = 2MB <= L2, m169 lesson); (b) 32 q-rows/wave so K LDS
// reads amortize 2x. LDS traffic/CU/tile: 256KB -> 64KB. XCD-chunked block
// swizzle clusters the 16 blocks of a head (x4 heads) on one XCD for L2 reuse.
#define TK 64
#define NTILE (SS / TK)   // 32
#define LDP 72            // padded LDS row stride (shorts)

__global__ __launch_bounds__(256, 2) void flash_attn(const unsigned short* __restrict__ Q,
                                                     const unsigned short* __restrict__ Kg,
                                                     const unsigned short* __restrict__ Vt,
                                                     unsigned short* __restrict__ ctx) {
    __shared__ alignas(16) unsigned short Ks[2][TK * LDP];
    const int t = threadIdx.x;
    const int lane = t & 63, wave = t >> 6;
    const int quad = lane >> 4, l15 = lane & 15;
    // XCD-chunked swizzle: 512 blocks, 8 XCDs -> chunk of 64 = 4 full heads/XCD.
    const int wg = (blockIdx.x & 7) * 64 + (blockIdx.x >> 3);
    const int qg = wg & 15;    // q-group within head (16 groups of 128 q)
    const int bh = wg >> 4;    // 0..31
    const int h = bh & 15, b = bh >> 4;
    const int q0 = (qg * 4 + wave) * 32;   // wave owns q0..q0+31 (two 16-q tiles)

    const unsigned short* Qb = Q + (size_t)b * SS * DD + h * HD;
    const unsigned short* Kb = Kg + (size_t)b * SS * DD + h * HD;
    const unsigned short* Vb = Vt + ((size_t)b * DD + h * HD) * SS;  // rows: hd, stride S

    const int r0 = t >> 3, cs = t & 7;
    const unsigned short* gK = Kb + (size_t)r0 * DD + cs * 8;
    const int ldsoff0 = r0 * LDP + cs * 8;
    const int ldsoff1 = (r0 + 32) * LDP + cs * 8;

    // per-j V row-group base pointers (rows j*16+l15, this lane's quad offset)
    const unsigned short* gV0 = Vb + (size_t)(0 * 16 + l15) * SS + quad * 4;
    const unsigned short* gV1 = Vb + (size_t)(1 * 16 + l15) * SS + quad * 4;
    const unsigned short* gV2 = Vb + (size_t)(2 * 16 + l15) * SS + quad * 4;
    const unsigned short* gV3 = Vb + (size_t)(3 * 16 + l15) * SS + quad * 4;

    bf16x8 qa[2][2];
#pragma unroll
    for (int qt = 0; qt < 2; qt++) {
        qa[qt][0] = *(const bf16x8*)(Qb + (size_t)(q0 + qt * 16 + l15) * DD + quad * 8);
        qa[qt][1] = *(const bf16x8*)(Qb + (size_t)(q0 + qt * 16 + l15) * DD + 32 + quad * 8);
    }

    float lrow[2] = {0.f, 0.f};
    f32x4 o[2][4];
#pragma unroll
    for (int qt = 0; qt < 2; qt++)
#pragma unroll
        for (int j = 0; j < 4; j++) o[qt][j] = (f32x4){0.f, 0.f, 0.f, 0.f};

    {
        uint4 kr0 = *(const uint4*)(gK);
        uint4 kr1 = *(const uint4*)(gK + (size_t)32 * DD);
        *(uint4*)&Ks[0][ldsoff0] = kr0;
        *(uint4*)&Ks[0][ldsoff1] = kr1;
    }
    __syncthreads();

    for (int tile = 0; tile < NTILE; ++tile) {
        const int buf = tile & 1;
        uint4 kr0, kr1;
        if (tile + 1 < NTILE) {
            const unsigned short* gKn = gK + (size_t)(tile + 1) * TK * DD;
            kr0 = *(const uint4*)(gKn);
            kr1 = *(const uint4*)(gKn + (size_t)32 * DD);
        }
        const unsigned short* Ksb = Ks[buf];
        const int vcol = tile * TK;
#pragma unroll
        for (int half = 0; half < 2; half++) {
            const int kb0 = half * 32;
            bf16x8 k0 = *(const bf16x8*)&Ksb[(kb0 + l15) * LDP + quad * 8];
            bf16x8 k1 = *(const bf16x8*)&Ksb[(kb0 + l15) * LDP + 32 + quad * 8];
            bf16x8 k2 = *(const bf16x8*)&Ksb[(kb0 + 16 + l15) * LDP + quad * 8];
            bf16x8 k3 = *(const bf16x8*)&Ksb[(kb0 + 16 + l15) * LDP + 32 + quad * 8];
            // V fragments direct from global (L2-resident per XCD)
            union { ushort4 s[2]; bf16x8 v; } af[4];
            af[0].s[0] = *(const ushort4*)(gV0 + vcol + kb0);
            af[0].s[1] = *(const ushort4*)(gV0 + vcol + kb0 + 16);
            af[1].s[0] = *(const ushort4*)(gV1 + vcol + kb0);
            af[1].s[1] = *(const ushort4*)(gV1 + vcol + kb0 + 16);
            af[2].s[0] = *(const ushort4*)(gV2 + vcol + kb0);
            af[2].s[1] = *(const ushort4*)(gV2 + vcol + kb0 + 16);
            af[3].s[0] = *(const ushort4*)(gV3 + vcol + kb0);
            af[3].s[1] = *(const ushort4*)(gV3 + vcol + kb0 + 16);
#pragma unroll
            for (int qt = 0; qt < 2; qt++) {
                f32x4 sc0 = (f32x4){0.f, 0.f, 0.f, 0.f};
                f32x4 sc1 = (f32x4){0.f, 0.f, 0.f, 0.f};
                __builtin_amdgcn_s_setprio(1);
                sc0 = mfma16(k0, qa[qt][0], sc0);
                sc0 = mfma16(k1, qa[qt][1], sc0);
                sc1 = mfma16(k2, qa[qt][0], sc1);
                sc1 = mfma16(k3, qa[qt][1], sc1);
                __builtin_amdgcn_s_setprio(0);

                float p[8];
#pragma unroll
                for (int rr = 0; rr < 4; rr++) {
                    p[rr]     = fast_exp2(sc0[rr]);
                    p[rr + 4] = fast_exp2(sc1[rr]);
                }
                lrow[qt] += (p[0] + p[1]) + (p[2] + p[3]) + (p[4] + p[5]) + (p[6] + p[7]);

                union { unsigned u[4]; bf16x8 v; } pf;
                pf.u[0] = pack2bf(p[0], p[1]);
                pf.u[1] = pack2bf(p[2], p[3]);
                pf.u[2] = pack2bf(p[4], p[5]);
                pf.u[3] = pack2bf(p[6], p[7]);

                __builtin_amdgcn_s_setprio(1);
#pragma unroll
                for (int j = 0; j < 4; j++)
                    o[qt][j] = mfma16(af[j].v, pf.v, o[qt][j]);
                __builtin_amdgcn_s_setprio(0);
            }
        }
        if (tile + 1 < NTILE) {
            __syncthreads();
            *(uint4*)&Ks[buf ^ 1][ldsoff0] = kr0;
            *(uint4*)&Ks[buf ^ 1][ldsoff1] = kr1;
            __syncthreads();
        }
    }

#pragma unroll
    for (int qt = 0; qt < 2; qt++) {
        float l = lrow[qt];
        l += __shfl_xor(l, 16, 64);
        l += __shfl_xor(l, 32, 64);
        float linv = 1.0f / l;
        unsigned short* crow = ctx + ((size_t)b * SS + q0 + qt * 16 + l15) * DD + h * HD;
#pragma unroll
        for (int j = 0; j < 4; j++) {
            uint2 w;
            w.x = pack2bf(o[qt][j][0] * linv, o[qt][j][1] * linv);
            w.y = pack2bf(o[qt][j][2] * linv, o[qt][j][3] * linv);
            *(uint2*)(crow + j * 16 + quad * 4) = w;
        }
    }
}

extern "C" void kernel_launch(void* const* d_in, const int* in_sizes, int n_in,
                              void* d_out, int out_size, void* d_ws, size_t ws_size,
                              hipStream_t stream) {
    const float* query = (const float*)d_in[0];
    const float* key   = (const float*)d_in[1];
    const float* value = (const float*)d_in[2];
    const float* Wq = (const float*)d_in[3];
    const float* bq = (const float*)d_in[4];
    const float* Wk = (const float*)d_in[5];
    const float* bk = (const float*)d_in[6];
    const float* Wv = (const float*)d_in[7];
    const float* bv = (const float*)d_in[8];
    const float* Wo = (const float*)d_in[9];
    const float* bo = (const float*)d_in[10];
    float* out = (float*)d_out;

    char* ws = (char*)d_ws;
    const size_t WSZ = (size_t)DD * DD * 2;       // 2 MB per transposed weight
    const size_t XSZ = (size_t)MM * DD * 2;       // 8 MB per activation
    unsigned short* Wqt = (unsigned short*)(ws + 0 * WSZ);
    unsigned short* Wkt = (unsigned short*)(ws + 1 * WSZ);
    unsigned short* Wvt = (unsigned short*)(ws + 2 * WSZ);
    unsigned short* Wot = (unsigned short*)(ws + 3 * WSZ);
    unsigned short* Xq  = (unsigned short*)(ws + 4 * WSZ);
    unsigned short* Xk  = (unsigned short*)(ws + 4 * WSZ + 1 * XSZ);
    unsigned short* Xv  = (unsigned short*)(ws + 4 * WSZ + 2 * XSZ);
    unsigned short* Qp  = (unsigned short*)(ws + 4 * WSZ + 3 * XSZ);
    unsigned short* Kp  = (unsigned short*)(ws + 4 * WSZ + 4 * XSZ);
    unsigned short* Vtp = (unsigned short*)(ws + 4 * WSZ + 5 * XSZ);  // [B][D][S] direct
    unsigned short* ctx = Xk;  // Xk dead after QKV GEMM

    // 1. fused prep: q/k/v bf16 converts (z=0..2) + 4 weight transposes (z=3..6)
    PrepArgs pargs;
    pargs.csrc[0] = query; pargs.csrc[1] = key; pargs.csrc[2] = value;
    pargs.cdst[0] = Xq; pargs.cdst[1] = Xk; pargs.cdst[2] = Xv;
    pargs.wsrc[0] = Wq; pargs.wsrc[1] = Wk; pargs.wsrc[2] = Wv; pargs.wsrc[3] = Wo;
    pargs.wdst[0] = Wqt; pargs.wdst[1] = Wkt; pargs.wdst[2] = Wvt; pargs.wdst[3] = Wot;
    prep_inputs<<<dim3(32, 32, 7), 256, 0, stream>>>(pargs);

    // 2. Q/K/V projections: 256x256 tile, 8 waves, 4-deep pipeline;
    //    z=2 writes V^T [B][D][S] directly (transpose fused)
    QKVArgs args;
    args.A[0] = Xq; args.A[1] = Xk; args.A[2] = Xv;
    args.Bt[0] = Wqt; args.Bt[1] = Wkt; args.Bt[2] = Wvt;
    args.bias[0] = bq; args.bias[1] = bk; args.bias[2] = bv;
    args.C[0] = Qp; args.C[1] = Kp; args.C[2] = Vtp;
    gemm_qkv<<<dim3(DD / 256, MM / 256, 3), 512, 0, stream>>>(args);

    // 3. flash attention: 512 blocks = 32 heads x 16 q-groups (4 waves x 32 q each)
    flash_attn<<<BB * HH * 16, 256, 0, stream>>>(Qp, Kp, Vtp, ctx);

    // 4. output projection -> fp32: 128x64 tiles, 512 blocks (2/CU)
    gemm_out<<<dim3(DD / 64, MM / 128), 256, 0, stream>>>(ctx, Wot, bo, out);
}

// Round 4
// 232.850 us; speedup vs baseline: 1.2886x; 1.2886x over previous
//
#include <hip/hip_runtime.h>
#include <hip/hip_bf16.h>

// Problem constants
#define BB 2
#define SS 2048
#define DD 1024
#define HH 16
#define HD 64
#define MM (BB*SS)   // 4096

typedef __attribute__((ext_vector_type(8))) short bf16x8;
typedef __attribute__((ext_vector_type(4))) float f32x4;

static __device__ inline unsigned short f2bf(float x) {
    unsigned int u = __float_as_uint(x);
    unsigned int r = (u + 0x7fffu + ((u >> 16) & 1u)) >> 16;
    return (unsigned short)r;
}

// packed f32x2 -> bf16x2 via v_cvt_pk_bf16_f32 (RNE, bit-identical to f2bf)
static __device__ inline unsigned pack2bf(float lo, float hi) {
    union { __hip_bfloat162 h; unsigned u; } c;
    c.h = __float22bfloat162_rn(make_float2(lo, hi));
    return c.u;
}

static __device__ inline f32x4 mfma16(bf16x8 a, bf16x8 b, f32x4 c) {
    return __builtin_amdgcn_mfma_f32_16x16x32_bf16(a, b, c, 0, 0, 0);
}

// raw v_exp_f32 (2^x)
static __device__ inline float fast_exp2(float x) {
    return __builtin_amdgcn_exp2f(x);
}

// async global->LDS 16B per lane: LDS dest = wave-uniform base + lane*16
typedef __attribute__((address_space(3))) unsigned int lds_u32;
typedef const __attribute__((address_space(1))) unsigned int glb_u32;
static __device__ inline void async_ld16(const void* g, void* l) {
    __builtin_amdgcn_global_load_lds((glb_u32*)g, (lds_u32*)l, 16, 0, 0);
}

// ---------------- fused prep: z<3 -> fp32->bf16 convert of q/k/v; z>=3 -> weight
// transpose+convert [R][C]fp32 -> [C][R]bf16.
struct PrepArgs {
    const float* csrc[3];
    unsigned short* cdst[3];
    const float* wsrc[4];
    unsigned short* wdst[4];
};
__global__ __launch_bounds__(256) void prep_inputs(PrepArgs args) {
    const int z = blockIdx.z;
    const int t = threadIdx.x;
    if (z < 3) {
        const float* in = args.csrc[z];
        unsigned short* out = args.cdst[z];
        int chunk = (blockIdx.y * 32 + blockIdx.x) * 4096;
#pragma unroll
        for (int r = 0; r < 4; r++) {
            int i = chunk + r * 1024 + t * 4;
            float4 v = *(const float4*)(in + i);
            uint2 o;
            o.x = pack2bf(v.x, v.y);
            o.y = pack2bf(v.z, v.w);
            *(uint2*)(out + i) = o;
        }
    } else {
        __shared__ float tile[32][33];
        const float* in = args.wsrc[z - 3];
        unsigned short* out = args.wdst[z - 3];
        int c0 = blockIdx.x * 32, r0 = blockIdx.y * 32;
        int x = t & 31, y0 = t >> 5;
        for (int yy = y0; yy < 32; yy += 8)
            tile[yy][x] = in[(size_t)(r0 + yy) * DD + c0 + x];
        __syncthreads();
        for (int yy = y0; yy < 32; yy += 8)
            out[(size_t)(c0 + yy) * DD + r0 + x] = f2bf(tile[x][yy]);
    }
}

struct QKVArgs {
    const unsigned short* A[3];
    const unsigned short* Bt[3];
    const float* bias[3];
    unsigned short* C[3];
};

// Q scale folds 1/sqrt(HD) AND log2(e) so flash can use exp2 directly.
#define QSCALE 0.1803368801111204f

// ---------------- QKV GEMM: 256x256 tile, BK=32, ring-4 pipeline, 8 waves ----------
// Round-4 change: split each K-step into 4 PHASES (m201-style fine interleave):
// each phase = {ds_read cluster -> issue 1 staging load -> raw s_barrier (no
// vmcnt drain) -> setprio(1) -> 8 MFMAs (one acc quadrant) -> setprio(0)}.
// Operand reads partitioned so nothing is read twice: P0: bfr[0..1]+af[0..3],
// P1: bfr[2..3], P2: af[4..7] (reuses af regs), P3: none.
// Counted vmcnt(8) at kt top (tiles kt+1,kt+2 stay in flight — never drain).
#define NBUF 4
#define NT (DD / 32)   // 32 K-tiles

__global__ __launch_bounds__(512, 2) void gemm_qkv(QKVArgs args) {
    __shared__ alignas(16) unsigned short AS[NBUF][256 * 32];
    __shared__ alignas(16) unsigned short BS[NBUF][256 * 32];
    const int z = blockIdx.z;
    const float scale = (z == 0) ? QSCALE : 1.0f;
    const unsigned short* __restrict__ A = args.A[z];
    const unsigned short* __restrict__ Bt = args.Bt[z];
    const float* __restrict__ bias = args.bias[z];
    unsigned short* __restrict__ C = args.C[z];
    const int K = DD, N = DD;
    const int t = threadIdx.x;
    const int lane = t & 63, wave = t >> 6;
    const int quad = lane >> 4, l15 = lane & 15;
    const int wm = wave & 1, wn = wave >> 1;    // 2 M-waves x 4 N-waves
    const int m0 = blockIdx.y * 256, n0 = blockIdx.x * 256;

    // Staging geometry: per tile, each thread issues 4x global_load_lds(16B).
    // Source slot is pre-swizzled so linear LDS dest + swizzled ds_read match.
    const int srow = wave * 16 + (lane >> 2);                 // 0..127
    const int sslot = (lane & 3) ^ ((lane >> 3) & 3);         // swizzled 16B slot
    const unsigned short* gA0 = A + (size_t)(m0 + srow) * K + sslot * 8;
    const unsigned short* gA1 = gA0 + (size_t)128 * K;
    const unsigned short* gB0 = Bt + (size_t)(n0 + srow) * K + sslot * 8;
    const unsigned short* gB1 = gB0 + (size_t)128 * K;
    const int rlo = wave * 512;            // LDS region (shorts): c=0
    const int rhi = wave * 512 + 4096;     // c=1 (rows 128..255)

    // ds_read swizzle: slot quad ^ ((l15>>1)&3), independent of fragment idx.
    const int swzq = quad ^ ((l15 >> 1) & 3);

    auto stage_all = [&](int kt) {
        const int b = kt & (NBUF - 1);
        const size_t ko = (size_t)kt * 32;
        async_ld16(gA0 + ko, &AS[b][rlo]);
        async_ld16(gA1 + ko, &AS[b][rhi]);
        async_ld16(gB0 + ko, &BS[b][rlo]);
        async_ld16(gB1 + ko, &BS[b][rhi]);
    };

    // prologue: 3 tiles in flight (12 loads outstanding)
    stage_all(0); stage_all(1); stage_all(2);

    f32x4 acc[8][4];
#pragma unroll
    for (int i = 0; i < 8; i++)
#pragma unroll
        for (int j = 0; j < 4; j++) acc[i][j] = (f32x4){0.f, 0.f, 0.f, 0.f};

#pragma unroll 4
    for (int kt = 0; kt < NT; ++kt) {
        // Wait tile kt staged; keep kt+1,kt+2 (8 loads) in flight.
        if (kt < NT - 2)       asm volatile("s_waitcnt vmcnt(8)" ::: "memory");
        else if (kt == NT - 2) asm volatile("s_waitcnt vmcnt(4)" ::: "memory");
        else                   asm volatile("s_waitcnt vmcnt(0)" ::: "memory");
        // Top barrier: all waves finished reading buf[(kt-1)&3] last iteration,
        // so staging into buf[(kt+3)&3] (same buffer) below is safe.
        asm volatile("s_barrier" ::: "memory");

        const bool pf = (kt + 3 < NT);
        const int bb = (kt + 3) & (NBUF - 1);
        const size_t ko = (size_t)(kt + 3) * 32;
        const unsigned short* Ab = AS[kt & (NBUF - 1)];
        const unsigned short* Bb = BS[kt & (NBUF - 1)];
        bf16x8 af[4], bfr[4];

        // ---- phase 0: bfr[0..1] + af rows 0..63; stage A-lo; quadrant (r0-3, c0-1)
#pragma unroll
        for (int j = 0; j < 2; j++)
            bfr[j] = *(const bf16x8*)&Bb[(wn * 64 + j * 16 + l15) * 32 + swzq * 8];
#pragma unroll
        for (int i = 0; i < 4; i++)
            af[i] = *(const bf16x8*)&Ab[(wm * 128 + i * 16 + l15) * 32 + swzq * 8];
        if (pf) async_ld16(gA0 + ko, &AS[bb][rlo]);
        asm volatile("s_barrier" ::: "memory");
        __builtin_amdgcn_s_setprio(1);
#pragma unroll
        for (int i = 0; i < 4; i++) {
            acc[i][0] = mfma16(af[i], bfr[0], acc[i][0]);
            acc[i][1] = mfma16(af[i], bfr[1], acc[i][1]);
        }
        __builtin_amdgcn_s_setprio(0);

        // ---- phase 1: bfr[2..3]; stage A-hi; quadrant (r0-3, c2-3)
#pragma unroll
        for (int j = 2; j < 4; j++)
            bfr[j] = *(const bf16x8*)&Bb[(wn * 64 + j * 16 + l15) * 32 + swzq * 8];
        if (pf) async_ld16(gA1 + ko, &AS[bb][rhi]);
        asm volatile("s_barrier" ::: "memory");
        __builtin_amdgcn_s_setprio(1);
#pragma unroll
        for (int i = 0; i < 4; i++) {
            acc[i][2] = mfma16(af[i], bfr[2], acc[i][2]);
            acc[i][3] = mfma16(af[i], bfr[3], acc[i][3]);
        }
        __builtin_amdgcn_s_setprio(0);

        // ---- phase 2: af rows 64..127; stage B-lo; quadrant (r4-7, c0-1)
#pragma unroll
        for (int i = 0; i < 4; i++)
            af[i] = *(const bf16x8*)&Ab[(wm * 128 + 64 + i * 16 + l15) * 32 + swzq * 8];
        if (pf) async_ld16(gB0 + ko, &BS[bb][rlo]);
        asm volatile("s_barrier" ::: "memory");
        __builtin_amdgcn_s_setprio(1);
#pragma unroll
        for (int i = 0; i < 4; i++) {
            acc[4 + i][0] = mfma16(af[i], bfr[0], acc[4 + i][0]);
            acc[4 + i][1] = mfma16(af[i], bfr[1], acc[4 + i][1]);
        }
        __builtin_amdgcn_s_setprio(0);

        // ---- phase 3: no reads; stage B-hi; quadrant (r4-7, c2-3)
        if (pf) async_ld16(gB1 + ko, &BS[bb][rhi]);
        asm volatile("s_barrier" ::: "memory");
        __builtin_amdgcn_s_setprio(1);
#pragma unroll
        for (int i = 0; i < 4; i++) {
            acc[4 + i][2] = mfma16(af[i], bfr[2], acc[4 + i][2]);
            acc[4 + i][3] = mfma16(af[i], bfr[3], acc[4 + i][3]);
        }
        __builtin_amdgcn_s_setprio(0);
    }

    if (z == 2) {
        // write C^T into [B][N][S]: token m = b*SS+s, dim col -> dst[b][col][s]
#pragma unroll
        for (int j = 0; j < 4; j++) {
            int col = n0 + wn * 64 + j * 16 + l15;
            float bv = bias[col];
#pragma unroll
            for (int i = 0; i < 8; i++) {
                int rowb = m0 + wm * 128 + i * 16 + quad * 4;
                int b = rowb >> 11, s = rowb & (SS - 1);
                uint2 w;
                w.x = pack2bf(acc[i][j][0] + bv, acc[i][j][1] + bv);
                w.y = pack2bf(acc[i][j][2] + bv, acc[i][j][3] + bv);
                *(uint2*)(C + (size_t)b * DD * SS + (size_t)col * SS + s) = w;
            }
        }
    } else {
#pragma unroll
        for (int j = 0; j < 4; j++) {
            int col = n0 + wn * 64 + j * 16 + l15;
            float bv = bias[col];
#pragma unroll
            for (int i = 0; i < 8; i++) {
                int rowb = m0 + wm * 128 + i * 16 + quad * 4;
#pragma unroll
                for (int rr = 0; rr < 4; rr++) {
                    float v = (acc[i][j][rr] + bv) * scale;
                    C[(size_t)(rowb + rr) * N + col] = f2bf(v);
                }
            }
        }
    }
}

// ---------------- 128x64-tile GEMM for the output projection -----------------------
__global__ __launch_bounds__(256) void gemm_out(const unsigned short* __restrict__ A,
                                                const unsigned short* __restrict__ Bt,
                                                const float* __restrict__ bias,
                                                float* __restrict__ C) {
    __shared__ alignas(16) unsigned short As[128 * 32];
    __shared__ alignas(16) unsigned short Bs[64 * 32];
    const int t = threadIdx.x;
    const int lane = t & 63, wave = t >> 6;
    const int quad = lane >> 4, l15 = lane & 15;
    const int m0 = blockIdx.y * 128, n0 = blockIdx.x * 64;
    const int K = DD, N = DD;

    const unsigned short* gA = A + (size_t)(m0 + wave * 16 + (lane >> 2)) * K + (lane & 3) * 8;
    const unsigned short* gB = Bt + (size_t)(n0 + wave * 16 + (lane >> 2)) * K + (lane & 3) * 8;
    unsigned short* lA0 = &As[(wave * 16) * 32];
    unsigned short* lA1 = &As[(wave * 16 + 64) * 32];
    unsigned short* lB0 = &Bs[(wave * 16) * 32];

    f32x4 acc[2][4];
#pragma unroll
    for (int i = 0; i < 2; i++)
#pragma unroll
        for (int j = 0; j < 4; j++) acc[i][j] = (f32x4){0.f, 0.f, 0.f, 0.f};

    for (int k0 = 0; k0 < K; k0 += 32) {
        __syncthreads();
        async_ld16(gA + k0, lA0);
        async_ld16(gA + (size_t)64 * K + k0, lA1);
        async_ld16(gB + k0, lB0);
        __syncthreads();

        bf16x8 af[2], bfr[4];
#pragma unroll
        for (int i = 0; i < 2; i++)
            af[i] = *(const bf16x8*)&As[(wave * 32 + i * 16 + l15) * 32 + quad * 8];
#pragma unroll
        for (int j = 0; j < 4; j++)
            bfr[j] = *(const bf16x8*)&Bs[(j * 16 + l15) * 32 + quad * 8];
#pragma unroll
        for (int i = 0; i < 2; i++)
#pragma unroll
            for (int j = 0; j < 4; j++)
                acc[i][j] = mfma16(af[i], bfr[j], acc[i][j]);
    }

#pragma unroll
    for (int j = 0; j < 4; j++) {
        int col = n0 + j * 16 + l15;
        float bv = bias[col];
#pragma unroll
        for (int i = 0; i < 2; i++) {
            int rowb = m0 + wave * 32 + i * 16 + quad * 4;
#pragma unroll
            for (int rr = 0; rr < 4; rr++)
                C[(size_t)(rowb + rr) * N + col] = acc[i][j][rr] + bv;
        }
    }
}

// ---------------- flash attention v5 (round-1 revert): LDS K/V, 32 q-rows/wave ------
// Round-3's V-from-global regressed 2.1x (V loads scatter 16 cachelines AND
// serialize the K prefetch through vmcnt ordering). This exact version measured
// 61.0 us (round 1); r1 vs r2 A/B showed occupancy/LDS-traffic knobs are neutral.
#define TK 64
#define NTILE (SS / TK)   // 32
#define LDP 72            // padded LDS row stride (shorts)

__global__ __launch_bounds__(256, 2) void flash_attn(const unsigned short* __restrict__ Q,
                                                     const unsigned short* __restrict__ Kg,
                                                     const unsigned short* __restrict__ Vt,
                                                     unsigned short* __restrict__ ctx) {
    __shared__ alignas(16) unsigned short Ks[2][TK * LDP];
    __shared__ alignas(16) unsigned short Vs[2][TK * LDP];
    const int t = threadIdx.x;
    const int lane = t & 63, wave = t >> 6;
    const int quad = lane >> 4, l15 = lane & 15;
    const int qg = blockIdx.x & 15;    // q-group within head (16 groups of 128 q)
    const int bh = blockIdx.x >> 4;    // 0..31
    const int h = bh & 15, b = bh >> 4;
    const int q0 = (qg * 4 + wave) * 32;   // wave owns q0..q0+31 (two 16-q tiles)

    const unsigned short* Qb = Q + (size_t)b * SS * DD + h * HD;
    const unsigned short* Kb = Kg + (size_t)b * SS * DD + h * HD;
    const unsigned short* Vb = Vt + ((size_t)b * DD + h * HD) * SS;  // rows: hd, stride S

    const int r0 = t >> 3, cs = t & 7;
    const unsigned short* gK = Kb + (size_t)r0 * DD + cs * 8;
    const unsigned short* gV = Vb + (size_t)r0 * SS + cs * 8;
    const int ldsoff0 = r0 * LDP + cs * 8;
    const int ldsoff1 = (r0 + 32) * LDP + cs * 8;

    bf16x8 qa[2][2];
#pragma unroll
    for (int qt = 0; qt < 2; qt++) {
        qa[qt][0] = *(const bf16x8*)(Qb + (size_t)(q0 + qt * 16 + l15) * DD + quad * 8);
        qa[qt][1] = *(const bf16x8*)(Qb + (size_t)(q0 + qt * 16 + l15) * DD + 32 + quad * 8);
    }

    float lrow[2] = {0.f, 0.f};
    f32x4 o[2][4];
#pragma unroll
    for (int qt = 0; qt < 2; qt++)
#pragma unroll
        for (int j = 0; j < 4; j++) o[qt][j] = (f32x4){0.f, 0.f, 0.f, 0.f};

    {
        uint4 kr0 = *(const uint4*)(gK);
        uint4 kr1 = *(const uint4*)(gK + (size_t)32 * DD);
        uint4 vr0 = *(const uint4*)(gV);
        uint4 vr1 = *(const uint4*)(gV + (size_t)32 * SS);
        *(uint4*)&Ks[0][ldsoff0] = kr0;
        *(uint4*)&Ks[0][ldsoff1] = kr1;
        *(uint4*)&Vs[0][ldsoff0] = vr0;
        *(uint4*)&Vs[0][ldsoff1] = vr1;
    }
    __syncthreads();

    for (int tile = 0; tile < NTILE; ++tile) {
        const int buf = tile & 1;
        uint4 kr0, kr1, vr0, vr1;
        if (tile + 1 < NTILE) {
            const unsigned short* gKn = gK + (size_t)(tile + 1) * TK * DD;
            const unsigned short* gVn = gV + (tile + 1) * TK;
            kr0 = *(const uint4*)(gKn);
            kr1 = *(const uint4*)(gKn + (size_t)32 * DD);
            vr0 = *(const uint4*)(gVn);
            vr1 = *(const uint4*)(gVn + (size_t)32 * SS);
        }
        const unsigned short* Ksb = Ks[buf];
        const unsigned short* Vsb = Vs[buf];
#pragma unroll
        for (int half = 0; half < 2; half++) {
            const int kb0 = half * 32;
            bf16x8 k0 = *(const bf16x8*)&Ksb[(kb0 + l15) * LDP + quad * 8];
            bf16x8 k1 = *(const bf16x8*)&Ksb[(kb0 + l15) * LDP + 32 + quad * 8];
            bf16x8 k2 = *(const bf16x8*)&Ksb[(kb0 + 16 + l15) * LDP + quad * 8];
            bf16x8 k3 = *(const bf16x8*)&Ksb[(kb0 + 16 + l15) * LDP + 32 + quad * 8];
            union { ushort4 s[2]; bf16x8 v; } af[4];
#pragma unroll
            for (int j = 0; j < 4; j++) {
                af[j].s[0] = *(const ushort4*)&Vsb[(j * 16 + l15) * LDP + kb0 + quad * 4];
                af[j].s[1] = *(const ushort4*)&Vsb[(j * 16 + l15) * LDP + kb0 + 16 + quad * 4];
            }
#pragma unroll
            for (int qt = 0; qt < 2; qt++) {
                f32x4 sc0 = (f32x4){0.f, 0.f, 0.f, 0.f};
                f32x4 sc1 = (f32x4){0.f, 0.f, 0.f, 0.f};
                sc0 = mfma16(k0, qa[qt][0], sc0);
                sc0 = mfma16(k1, qa[qt][1], sc0);
                sc1 = mfma16(k2, qa[qt][0], sc1);
                sc1 = mfma16(k3, qa[qt][1], sc1);

                float p[8];
#pragma unroll
                for (int rr = 0; rr < 4; rr++) {
                    p[rr]     = fast_exp2(sc0[rr]);
                    p[rr + 4] = fast_exp2(sc1[rr]);
                }
                lrow[qt] += (p[0] + p[1]) + (p[2] + p[3]) + (p[4] + p[5]) + (p[6] + p[7]);

                union { unsigned u[4]; bf16x8 v; } pf;
                pf.u[0] = pack2bf(p[0], p[1]);
                pf.u[1] = pack2bf(p[2], p[3]);
                pf.u[2] = pack2bf(p[4], p[5]);
                pf.u[3] = pack2bf(p[6], p[7]);

#pragma unroll
                for (int j = 0; j < 4; j++)
                    o[qt][j] = mfma16(af[j].v, pf.v, o[qt][j]);
            }
        }
        if (tile + 1 < NTILE) {
            __syncthreads();
            *(uint4*)&Ks[buf ^ 1][ldsoff0] = kr0;
            *(uint4*)&Ks[buf ^ 1][ldsoff1] = kr1;
            *(uint4*)&Vs[buf ^ 1][ldsoff0] = vr0;
            *(uint4*)&Vs[buf ^ 1][ldsoff1] = vr1;
            __syncthreads();
        }
    }

#pragma unroll
    for (int qt = 0; qt < 2; qt++) {
        float l = lrow[qt];
        l += __shfl_xor(l, 16, 64);
        l += __shfl_xor(l, 32, 64);
        float linv = 1.0f / l;
        unsigned short* crow = ctx + ((size_t)b * SS + q0 + qt * 16 + l15) * DD + h * HD;
#pragma unroll
        for (int j = 0; j < 4; j++) {
            uint2 w;
            w.x = pack2bf(o[qt][j][0] * linv, o[qt][j][1] * linv);
            w.y = pack2bf(o[qt][j][2] * linv, o[qt][j][3] * linv);
            *(uint2*)(crow + j * 16 + quad * 4) = w;
        }
    }
}

extern "C" void kernel_launch(void* const* d_in, const int* in_sizes, int n_in,
                              void* d_out, int out_size, void* d_ws, size_t ws_size,
                              hipStream_t stream) {
    const float* query = (const float*)d_in[0];
    const float* key   = (const float*)d_in[1];
    const float* value = (const float*)d_in[2];
    const float* Wq = (const float*)d_in[3];
    const float* bq = (const float*)d_in[4];
    const float* Wk = (const float*)d_in[5];
    const float* bk = (const float*)d_in[6];
    const float* Wv = (const float*)d_in[7];
    const float* bv = (const float*)d_in[8];
    const float* Wo = (const float*)d_in[9];
    const float* bo = (const float*)d_in[10];
    float* out = (float*)d_out;

    char* ws = (char*)d_ws;
    const size_t WSZ = (size_t)DD * DD * 2;       // 2 MB per transposed weight
    const size_t XSZ = (size_t)MM * DD * 2;       // 8 MB per activation
    unsigned short* Wqt = (unsigned short*)(ws + 0 * WSZ);
    unsigned short* Wkt = (unsigned short*)(ws + 1 * WSZ);
    unsigned short* Wvt = (unsigned short*)(ws + 2 * WSZ);
    unsigned short* Wot = (unsigned short*)(ws + 3 * WSZ);
    unsigned short* Xq  = (unsigned short*)(ws + 4 * WSZ);
    unsigned short* Xk  = (unsigned short*)(ws + 4 * WSZ + 1 * XSZ);
    unsigned short* Xv  = (unsigned short*)(ws + 4 * WSZ + 2 * XSZ);
    unsigned short* Qp  = (unsigned short*)(ws + 4 * WSZ + 3 * XSZ);
    unsigned short* Kp  = (unsigned short*)(ws + 4 * WSZ + 4 * XSZ);
    unsigned short* Vtp = (unsigned short*)(ws + 4 * WSZ + 5 * XSZ);  // [B][D][S] direct
    unsigned short* ctx = Xk;  // Xk dead after QKV GEMM

    // 1. fused prep: q/k/v bf16 converts (z=0..2) + 4 weight transposes (z=3..6)
    PrepArgs pargs;
    pargs.csrc[0] = query; pargs.csrc[1] = key; pargs.csrc[2] = value;
    pargs.cdst[0] = Xq; pargs.cdst[1] = Xk; pargs.cdst[2] = Xv;
    pargs.wsrc[0] = Wq; pargs.wsrc[1] = Wk; pargs.wsrc[2] = Wv; pargs.wsrc[3] = Wo;
    pargs.wdst[0] = Wqt; pargs.wdst[1] = Wkt; pargs.wdst[2] = Wvt; pargs.wdst[3] = Wot;
    prep_inputs<<<dim3(32, 32, 7), 256, 0, stream>>>(pargs);

    // 2. Q/K/V projections: 256x256 tile, 8 waves, ring-4 + 4-phase interleave;
    //    z=2 writes V^T [B][D][S] directly (transpose fused)
    QKVArgs args;
    args.A[0] = Xq; args.A[1] = Xk; args.A[2] = Xv;
    args.Bt[0] = Wqt; args.Bt[1] = Wkt; args.Bt[2] = Wvt;
    args.bias[0] = bq; args.bias[1] = bk; args.bias[2] = bv;
    args.C[0] = Qp; args.C[1] = Kp; args.C[2] = Vtp;
    gemm_qkv<<<dim3(DD / 256, MM / 256, 3), 512, 0, stream>>>(args);

    // 3. flash attention: 512 blocks = 32 heads x 16 q-groups (4 waves x 32 q each)
    flash_attn<<<BB * HH * 16, 256, 0, stream>>>(Qp, Kp, Vtp, ctx);

    // 4. output projection -> fp32: 128x64 tiles, 512 blocks (2/CU)
    gemm_out<<<dim3(DD / 64, MM / 128), 256, 0, stream>>>(ctx, Wot, bo, out);
}

// Round 5
// 227.591 us; speedup vs baseline: 1.3184x; 1.0231x over previous
//
#include <hip/hip_runtime.h>
#include <hip/hip_bf16.h>

// Problem constants
#define BB 2
#define SS 2048
#define DD 1024
#define HH 16
#define HD 64
#define MM (BB*SS)   // 4096

typedef __attribute__((ext_vector_type(8))) short bf16x8;
typedef __attribute__((ext_vector_type(4))) float f32x4;

static __device__ inline unsigned short f2bf(float x) {
    unsigned int u = __float_as_uint(x);
    unsigned int r = (u + 0x7fffu + ((u >> 16) & 1u)) >> 16;
    return (unsigned short)r;
}

// packed f32x2 -> bf16x2 via v_cvt_pk_bf16_f32 (RNE, bit-identical to f2bf)
static __device__ inline unsigned pack2bf(float lo, float hi) {
    union { __hip_bfloat162 h; unsigned u; } c;
    c.h = __float22bfloat162_rn(make_float2(lo, hi));
    return c.u;
}

static __device__ inline f32x4 mfma16(bf16x8 a, bf16x8 b, f32x4 c) {
    return __builtin_amdgcn_mfma_f32_16x16x32_bf16(a, b, c, 0, 0, 0);
}

// raw v_exp_f32 (2^x)
static __device__ inline float fast_exp2(float x) {
    return __builtin_amdgcn_exp2f(x);
}

// async global->LDS 16B per lane: LDS dest = wave-uniform base + lane*16
typedef __attribute__((address_space(3))) unsigned int lds_u32;
typedef const __attribute__((address_space(1))) unsigned int glb_u32;
static __device__ inline void async_ld16(const void* g, void* l) {
    __builtin_amdgcn_global_load_lds((glb_u32*)g, (lds_u32*)l, 16, 0, 0);
}

// ---------------- fused prep: z<3 -> fp32->bf16 convert of q/k/v; z>=3 -> weight
// transpose+convert [R][C]fp32 -> [C][R]bf16.
struct PrepArgs {
    const float* csrc[3];
    unsigned short* cdst[3];
    const float* wsrc[4];
    unsigned short* wdst[4];
};
__global__ __launch_bounds__(256) void prep_inputs(PrepArgs args) {
    const int z = blockIdx.z;
    const int t = threadIdx.x;
    if (z < 3) {
        const float* in = args.csrc[z];
        unsigned short* out = args.cdst[z];
        int chunk = (blockIdx.y * 32 + blockIdx.x) * 4096;
#pragma unroll
        for (int r = 0; r < 4; r++) {
            int i = chunk + r * 1024 + t * 4;
            float4 v = *(const float4*)(in + i);
            uint2 o;
            o.x = pack2bf(v.x, v.y);
            o.y = pack2bf(v.z, v.w);
            *(uint2*)(out + i) = o;
        }
    } else {
        __shared__ float tile[32][33];
        const float* in = args.wsrc[z - 3];
        unsigned short* out = args.wdst[z - 3];
        int c0 = blockIdx.x * 32, r0 = blockIdx.y * 32;
        int x = t & 31, y0 = t >> 5;
        for (int yy = y0; yy < 32; yy += 8)
            tile[yy][x] = in[(size_t)(r0 + yy) * DD + c0 + x];
        __syncthreads();
        for (int yy = y0; yy < 32; yy += 8)
            out[(size_t)(c0 + yy) * DD + r0 + x] = f2bf(tile[x][yy]);
    }
}

struct QKVArgs {
    const unsigned short* A[3];
    const unsigned short* Bt[3];
    const float* bias[3];
    unsigned short* C[3];
};

// Q scale folds 1/sqrt(HD) AND log2(e) so flash can use exp2 directly.
#define QSCALE 0.1803368801111204f

// ---------------- QKV GEMM: m201-faithful 256x256, BK=64, 2-buf, 4-phase/K-tile ----
// Round-5 change: BK=32 rings (r1 coarse, r4 4-phase) both measured ~53 us (~8%
// MFMA eff). The proven m201 regime needs BK=64 + 16-MFMA phases + ONE counted
// vmcnt per K-tile. Geometry = m201 exactly: 512 thr, 8 waves (2Mx4N), per-wave
// 128x64 out, LDS 2 x (A 256x64 + B 256x64) bf16 = 128 KiB.
// Schedule per K-tile t (4 phases):
//   start: s_waitcnt vmcnt(4)  [t+1's H0,H1 in flight stay] ; s_barrier
//   P0: read af[0..3][kk], bf[0..1][kk]; issue t+1.B-lo; bar; prio1; 16 MFMA; prio0; bar
//   P1: read bf[2..3][kk];               issue t+1.B-hi; bar; 16 MFMA; bar
//   P2: read af[4..7][kk] (reuse regs);  issue t+2.A-lo; bar; 16 MFMA; bar
//   P3: no reads;                        issue t+2.A-hi; bar; 16 MFMA
// FIFO: ... t.H2(t-1.P0) t.H3(t-1.P1) t+1.H0(t-1.P2) t+1.H1(t-1.P3) -> vmcnt(4)
// at t-start guarantees ALL of tile t resident. Writes into buf[t&1] at t.P2/P3
// target regions whose reads completed (lgkmcnt'd) >=1 phase-barrier earlier.
// Swizzle (both sides): 16B slot' = slot ^ (row&7); rows are 128B so bank =
// f(slot') only -> 64 lanes spread 8 per 16B-slot = balanced conflict-free.
#define NKT 16   // K / 64

__global__ __launch_bounds__(512, 2) void gemm_qkv(QKVArgs args) {
    __shared__ alignas(16) unsigned short AS[2][256 * 64];
    __shared__ alignas(16) unsigned short BS[2][256 * 64];
    const int z = blockIdx.z;
    const float scale = (z == 0) ? QSCALE : 1.0f;
    const unsigned short* __restrict__ A = args.A[z];
    const unsigned short* __restrict__ Bt = args.Bt[z];
    const float* __restrict__ bias = args.bias[z];
    unsigned short* __restrict__ C = args.C[z];
    const int K = DD, N = DD;
    const int t = threadIdx.x;
    const int lane = t & 63, wave = t >> 6;
    const int quad = lane >> 4, l15 = lane & 15;
    const int wm = wave & 1, wn = wave >> 1;    // 2 M-waves x 4 N-waves
    const int m0 = blockIdx.y * 256, n0 = blockIdx.x * 256;

    // Staging: thread covers row (t>>3) within each 64-row load-group, 16B slot
    // (t&7). Source col pre-swizzled by slot ^ (row&7) so linear LDS dest +
    // swizzled ds_read return the right data.
    const int srow = t >> 3;                     // 0..63
    const int cslot = (t & 7) ^ (srow & 7);      // pre-swizzled source 16B slot
    const unsigned short* gA = A + (size_t)(m0 + srow) * K + cslot * 8;
    const unsigned short* gB = Bt + (size_t)(n0 + srow) * K + cslot * 8;
    const int dstoff = srow * 64 + (t & 7) * 8;  // shorts, within 64-row group

    auto stageA = [&](int tl, int h) {   // h: 0 = rows 0..127, 1 = rows 128..255
        unsigned short* d = &AS[tl & 1][h * 128 * 64 + dstoff];
        const unsigned short* s = gA + (size_t)(h * 128) * K + (size_t)tl * 64;
        async_ld16(s, d);
        async_ld16(s + (size_t)64 * K, d + 64 * 64);
    };
    auto stageB = [&](int tl, int h) {
        unsigned short* d = &BS[tl & 1][h * 128 * 64 + dstoff];
        const unsigned short* s = gB + (size_t)(h * 128) * K + (size_t)tl * 64;
        async_ld16(s, d);
        async_ld16(s + (size_t)64 * K, d + 64 * 64);
    };

    // prologue: T0 fully (8 loads) + T1.A-lo, T1.A-hi (4 loads) = 12 in flight
    stageA(0, 0); stageA(0, 1); stageB(0, 0); stageB(0, 1);
    stageA(1, 0); stageA(1, 1);

    f32x4 acc[8][4];
#pragma unroll
    for (int i = 0; i < 8; i++)
#pragma unroll
        for (int j = 0; j < 4; j++) acc[i][j] = (f32x4){0.f, 0.f, 0.f, 0.f};

#pragma unroll 2
    for (int kt = 0; kt < NKT; ++kt) {
        if (kt < NKT - 1) asm volatile("s_waitcnt vmcnt(4)" ::: "memory");
        else              asm volatile("s_waitcnt vmcnt(0)" ::: "memory");
        __builtin_amdgcn_s_barrier();

        const unsigned short* Ab = AS[kt & 1];
        const unsigned short* Bb = BS[kt & 1];
        bf16x8 af[4][2], bf[4][2];

        // ---- P0: af rows 0..63 of wave-half + bf cols 0..31; issue t+1.B-lo
#pragma unroll
        for (int i = 0; i < 4; i++) {
            const int row = wm * 128 + i * 16 + l15;
#pragma unroll
            for (int kk = 0; kk < 2; kk++)
                af[i][kk] = *(const bf16x8*)&Ab[row * 64 + ((kk * 4 + quad) ^ (l15 & 7)) * 8];
        }
#pragma unroll
        for (int j = 0; j < 2; j++) {
            const int row = wn * 64 + j * 16 + l15;
#pragma unroll
            for (int kk = 0; kk < 2; kk++)
                bf[j][kk] = *(const bf16x8*)&Bb[row * 64 + ((kk * 4 + quad) ^ (l15 & 7)) * 8];
        }
        if (kt + 1 < NKT) stageB(kt + 1, 0);
        __builtin_amdgcn_s_barrier();
        __builtin_amdgcn_s_setprio(1);
#pragma unroll
        for (int i = 0; i < 4; i++)
#pragma unroll
            for (int j = 0; j < 2; j++) {
                acc[i][j] = mfma16(af[i][0], bf[j][0], acc[i][j]);
                acc[i][j] = mfma16(af[i][1], bf[j][1], acc[i][j]);
            }
        __builtin_amdgcn_s_setprio(0);
        __builtin_amdgcn_s_barrier();

        // ---- P1: bf cols 32..63; issue t+1.B-hi
#pragma unroll
        for (int j = 2; j < 4; j++) {
            const int row = wn * 64 + j * 16 + l15;
#pragma unroll
            for (int kk = 0; kk < 2; kk++)
                bf[j][kk] = *(const bf16x8*)&Bb[row * 64 + ((kk * 4 + quad) ^ (l15 & 7)) * 8];
        }
        if (kt + 1 < NKT) stageB(kt + 1, 1);
        __builtin_amdgcn_s_barrier();
        __builtin_amdgcn_s_setprio(1);
#pragma unroll
        for (int i = 0; i < 4; i++)
#pragma unroll
            for (int j = 2; j < 4; j++) {
                acc[i][j] = mfma16(af[i][0], bf[j][0], acc[i][j]);
                acc[i][j] = mfma16(af[i][1], bf[j][1], acc[i][j]);
            }
        __builtin_amdgcn_s_setprio(0);
        __builtin_amdgcn_s_barrier();

        // ---- P2: af rows 64..127 of wave-half (reuse regs); issue t+2.A-lo
#pragma unroll
        for (int i = 0; i < 4; i++) {
            const int row = wm * 128 + 64 + i * 16 + l15;
#pragma unroll
            for (int kk = 0; kk < 2; kk++)
                af[i][kk] = *(const bf16x8*)&Ab[row * 64 + ((kk * 4 + quad) ^ (l15 & 7)) * 8];
        }
        if (kt + 2 < NKT) stageA(kt + 2, 0);
        __builtin_amdgcn_s_barrier();
        __builtin_amdgcn_s_setprio(1);
#pragma unroll
        for (int i = 0; i < 4; i++)
#pragma unroll
            for (int j = 0; j < 2; j++) {
                acc[4 + i][j] = mfma16(af[i][0], bf[j][0], acc[4 + i][j]);
                acc[4 + i][j] = mfma16(af[i][1], bf[j][1], acc[4 + i][j]);
            }
        __builtin_amdgcn_s_setprio(0);
        __builtin_amdgcn_s_barrier();

        // ---- P3: no reads; issue t+2.A-hi
        if (kt + 2 < NKT) stageA(kt + 2, 1);
        __builtin_amdgcn_s_barrier();
        __builtin_amdgcn_s_setprio(1);
#pragma unroll
        for (int i = 0; i < 4; i++)
#pragma unroll
            for (int j = 2; j < 4; j++) {
                acc[4 + i][j] = mfma16(af[i][0], bf[j][0], acc[4 + i][j]);
                acc[4 + i][j] = mfma16(af[i][1], bf[j][1], acc[4 + i][j]);
            }
        __builtin_amdgcn_s_setprio(0);
        // no trailing barrier: next K-tile starts with vmcnt + s_barrier
    }

    if (z == 2) {
        // write C^T into [B][N][S]: token m = b*SS+s, dim col -> dst[b][col][s]
#pragma unroll
        for (int j = 0; j < 4; j++) {
            int col = n0 + wn * 64 + j * 16 + l15;
            float bv = bias[col];
#pragma unroll
            for (int i = 0; i < 8; i++) {
                int rowb = m0 + wm * 128 + i * 16 + quad * 4;
                int b = rowb >> 11, s = rowb & (SS - 1);
                uint2 w;
                w.x = pack2bf(acc[i][j][0] + bv, acc[i][j][1] + bv);
                w.y = pack2bf(acc[i][j][2] + bv, acc[i][j][3] + bv);
                *(uint2*)(C + (size_t)b * DD * SS + (size_t)col * SS + s) = w;
            }
        }
    } else {
#pragma unroll
        for (int j = 0; j < 4; j++) {
            int col = n0 + wn * 64 + j * 16 + l15;
            float bv = bias[col];
#pragma unroll
            for (int i = 0; i < 8; i++) {
                int rowb = m0 + wm * 128 + i * 16 + quad * 4;
#pragma unroll
                for (int rr = 0; rr < 4; rr++) {
                    float v = (acc[i][j][rr] + bv) * scale;
                    C[(size_t)(rowb + rr) * N + col] = f2bf(v);
                }
            }
        }
    }
}

// ---------------- 128x64-tile GEMM for the output projection -----------------------
__global__ __launch_bounds__(256) void gemm_out(const unsigned short* __restrict__ A,
                                                const unsigned short* __restrict__ Bt,
                                                const float* __restrict__ bias,
                                                float* __restrict__ C) {
    __shared__ alignas(16) unsigned short As[128 * 32];
    __shared__ alignas(16) unsigned short Bs[64 * 32];
    const int t = threadIdx.x;
    const int lane = t & 63, wave = t >> 6;
    const int quad = lane >> 4, l15 = lane & 15;
    const int m0 = blockIdx.y * 128, n0 = blockIdx.x * 64;
    const int K = DD, N = DD;

    const unsigned short* gA = A + (size_t)(m0 + wave * 16 + (lane >> 2)) * K + (lane & 3) * 8;
    const unsigned short* gB = Bt + (size_t)(n0 + wave * 16 + (lane >> 2)) * K + (lane & 3) * 8;
    unsigned short* lA0 = &As[(wave * 16) * 32];
    unsigned short* lA1 = &As[(wave * 16 + 64) * 32];
    unsigned short* lB0 = &Bs[(wave * 16) * 32];

    f32x4 acc[2][4];
#pragma unroll
    for (int i = 0; i < 2; i++)
#pragma unroll
        for (int j = 0; j < 4; j++) acc[i][j] = (f32x4){0.f, 0.f, 0.f, 0.f};

    for (int k0 = 0; k0 < K; k0 += 32) {
        __syncthreads();
        async_ld16(gA + k0, lA0);
        async_ld16(gA + (size_t)64 * K + k0, lA1);
        async_ld16(gB + k0, lB0);
        __syncthreads();

        bf16x8 af[2], bfr[4];
#pragma unroll
        for (int i = 0; i < 2; i++)
            af[i] = *(const bf16x8*)&As[(wave * 32 + i * 16 + l15) * 32 + quad * 8];
#pragma unroll
        for (int j = 0; j < 4; j++)
            bfr[j] = *(const bf16x8*)&Bs[(j * 16 + l15) * 32 + quad * 8];
#pragma unroll
        for (int i = 0; i < 2; i++)
#pragma unroll
            for (int j = 0; j < 4; j++)
                acc[i][j] = mfma16(af[i], bfr[j], acc[i][j]);
    }

#pragma unroll
    for (int j = 0; j < 4; j++) {
        int col = n0 + j * 16 + l15;
        float bv = bias[col];
#pragma unroll
        for (int i = 0; i < 2; i++) {
            int rowb = m0 + wave * 32 + i * 16 + quad * 4;
#pragma unroll
            for (int rr = 0; rr < 4; rr++)
                C[(size_t)(rowb + rr) * N + col] = acc[i][j][rr] + bv;
        }
    }
}

// ---------------- flash attention v5 (round-1 config): LDS K/V, 32 q-rows/wave ------
#define TK 64
#define NTILE (SS / TK)   // 32
#define LDP 72            // padded LDS row stride (shorts)

__global__ __launch_bounds__(256, 2) void flash_attn(const unsigned short* __restrict__ Q,
                                                     const unsigned short* __restrict__ Kg,
                                                     const unsigned short* __restrict__ Vt,
                                                     unsigned short* __restrict__ ctx) {
    __shared__ alignas(16) unsigned short Ks[2][TK * LDP];
    __shared__ alignas(16) unsigned short Vs[2][TK * LDP];
    const int t = threadIdx.x;
    const int lane = t & 63, wave = t >> 6;
    const int quad = lane >> 4, l15 = lane & 15;
    const int qg = blockIdx.x & 15;    // q-group within head (16 groups of 128 q)
    const int bh = blockIdx.x >> 4;    // 0..31
    const int h = bh & 15, b = bh >> 4;
    const int q0 = (qg * 4 + wave) * 32;   // wave owns q0..q0+31 (two 16-q tiles)

    const unsigned short* Qb = Q + (size_t)b * SS * DD + h * HD;
    const unsigned short* Kb = Kg + (size_t)b * SS * DD + h * HD;
    const unsigned short* Vb = Vt + ((size_t)b * DD + h * HD) * SS;  // rows: hd, stride S

    const int r0 = t >> 3, cs = t & 7;
    const unsigned short* gK = Kb + (size_t)r0 * DD + cs * 8;
    const unsigned short* gV = Vb + (size_t)r0 * SS + cs * 8;
    const int ldsoff0 = r0 * LDP + cs * 8;
    const int ldsoff1 = (r0 + 32) * LDP + cs * 8;

    bf16x8 qa[2][2];
#pragma unroll
    for (int qt = 0; qt < 2; qt++) {
        qa[qt][0] = *(const bf16x8*)(Qb + (size_t)(q0 + qt * 16 + l15) * DD + quad * 8);
        qa[qt][1] = *(const bf16x8*)(Qb + (size_t)(q0 + qt * 16 + l15) * DD + 32 + quad * 8);
    }

    float lrow[2] = {0.f, 0.f};
    f32x4 o[2][4];
#pragma unroll
    for (int qt = 0; qt < 2; qt++)
#pragma unroll
        for (int j = 0; j < 4; j++) o[qt][j] = (f32x4){0.f, 0.f, 0.f, 0.f};

    {
        uint4 kr0 = *(const uint4*)(gK);
        uint4 kr1 = *(const uint4*)(gK + (size_t)32 * DD);
        uint4 vr0 = *(const uint4*)(gV);
        uint4 vr1 = *(const uint4*)(gV + (size_t)32 * SS);
        *(uint4*)&Ks[0][ldsoff0] = kr0;
        *(uint4*)&Ks[0][ldsoff1] = kr1;
        *(uint4*)&Vs[0][ldsoff0] = vr0;
        *(uint4*)&Vs[0][ldsoff1] = vr1;
    }
    __syncthreads();

    for (int tile = 0; tile < NTILE; ++tile) {
        const int buf = tile & 1;
        uint4 kr0, kr1, vr0, vr1;
        if (tile + 1 < NTILE) {
            const unsigned short* gKn = gK + (size_t)(tile + 1) * TK * DD;
            const unsigned short* gVn = gV + (tile + 1) * TK;
            kr0 = *(const uint4*)(gKn);
            kr1 = *(const uint4*)(gKn + (size_t)32 * DD);
            vr0 = *(const uint4*)(gVn);
            vr1 = *(const uint4*)(gVn + (size_t)32 * SS);
        }
        const unsigned short* Ksb = Ks[buf];
        const unsigned short* Vsb = Vs[buf];
#pragma unroll
        for (int half = 0; half < 2; half++) {
            const int kb0 = half * 32;
            bf16x8 k0 = *(const bf16x8*)&Ksb[(kb0 + l15) * LDP + quad * 8];
            bf16x8 k1 = *(const bf16x8*)&Ksb[(kb0 + l15) * LDP + 32 + quad * 8];
            bf16x8 k2 = *(const bf16x8*)&Ksb[(kb0 + 16 + l15) * LDP + quad * 8];
            bf16x8 k3 = *(const bf16x8*)&Ksb[(kb0 + 16 + l15) * LDP + 32 + quad * 8];
            union { ushort4 s[2]; bf16x8 v; } af[4];
#pragma unroll
            for (int j = 0; j < 4; j++) {
                af[j].s[0] = *(const ushort4*)&Vsb[(j * 16 + l15) * LDP + kb0 + quad * 4];
                af[j].s[1] = *(const ushort4*)&Vsb[(j * 16 + l15) * LDP + kb0 + 16 + quad * 4];
            }
#pragma unroll
            for (int qt = 0; qt < 2; qt++) {
                f32x4 sc0 = (f32x4){0.f, 0.f, 0.f, 0.f};
                f32x4 sc1 = (f32x4){0.f, 0.f, 0.f, 0.f};
                sc0 = mfma16(k0, qa[qt][0], sc0);
                sc0 = mfma16(k1, qa[qt][1], sc0);
                sc1 = mfma16(k2, qa[qt][0], sc1);
                sc1 = mfma16(k3, qa[qt][1], sc1);

                float p[8];
#pragma unroll
                for (int rr = 0; rr < 4; rr++) {
                    p[rr]     = fast_exp2(sc0[rr]);
                    p[rr + 4] = fast_exp2(sc1[rr]);
                }
                lrow[qt] += (p[0] + p[1]) + (p[2] + p[3]) + (p[4] + p[5]) + (p[6] + p[7]);

                union { unsigned u[4]; bf16x8 v; } pf;
                pf.u[0] = pack2bf(p[0], p[1]);
                pf.u[1] = pack2bf(p[2], p[3]);
                pf.u[2] = pack2bf(p[4], p[5]);
                pf.u[3] = pack2bf(p[6], p[7]);

#pragma unroll
                for (int j = 0; j < 4; j++)
                    o[qt][j] = mfma16(af[j].v, pf.v, o[qt][j]);
            }
        }
        if (tile + 1 < NTILE) {
            __syncthreads();
            *(uint4*)&Ks[buf ^ 1][ldsoff0] = kr0;
            *(uint4*)&Ks[buf ^ 1][ldsoff1] = kr1;
            *(uint4*)&Vs[buf ^ 1][ldsoff0] = vr0;
            *(uint4*)&Vs[buf ^ 1][ldsoff1] = vr1;
            __syncthreads();
        }
    }

#pragma unroll
    for (int qt = 0; qt < 2; qt++) {
        float l = lrow[qt];
        l += __shfl_xor(l, 16, 64);
        l += __shfl_xor(l, 32, 64);
        float linv = 1.0f / l;
        unsigned short* crow = ctx + ((size_t)b * SS + q0 + qt * 16 + l15) * DD + h * HD;
#pragma unroll
        for (int j = 0; j < 4; j++) {
            uint2 w;
            w.x = pack2bf(o[qt][j][0] * linv, o[qt][j][1] * linv);
            w.y = pack2bf(o[qt][j][2] * linv, o[qt][j][3] * linv);
            *(uint2*)(crow + j * 16 + quad * 4) = w;
        }
    }
}

extern "C" void kernel_launch(void* const* d_in, const int* in_sizes, int n_in,
                              void* d_out, int out_size, void* d_ws, size_t ws_size,
                              hipStream_t stream) {
    const float* query = (const float*)d_in[0];
    const float* key   = (const float*)d_in[1];
    const float* value = (const float*)d_in[2];
    const float* Wq = (const float*)d_in[3];
    const float* bq = (const float*)d_in[4];
    const float* Wk = (const float*)d_in[5];
    const float* bk = (const float*)d_in[6];
    const float* Wv = (const float*)d_in[7];
    const float* bv = (const float*)d_in[8];
    const float* Wo = (const float*)d_in[9];
    const float* bo = (const float*)d_in[10];
    float* out = (float*)d_out;

    char* ws = (char*)d_ws;
    const size_t WSZ = (size_t)DD * DD * 2;       // 2 MB per transposed weight
    const size_t XSZ = (size_t)MM * DD * 2;       // 8 MB per activation
    unsigned short* Wqt = (unsigned short*)(ws + 0 * WSZ);
    unsigned short* Wkt = (unsigned short*)(ws + 1 * WSZ);
    unsigned short* Wvt = (unsigned short*)(ws + 2 * WSZ);
    unsigned short* Wot = (unsigned short*)(ws + 3 * WSZ);
    unsigned short* Xq  = (unsigned short*)(ws + 4 * WSZ);
    unsigned short* Xk  = (unsigned short*)(ws + 4 * WSZ + 1 * XSZ);
    unsigned short* Xv  = (unsigned short*)(ws + 4 * WSZ + 2 * XSZ);
    unsigned short* Qp  = (unsigned short*)(ws + 4 * WSZ + 3 * XSZ);
    unsigned short* Kp  = (unsigned short*)(ws + 4 * WSZ + 4 * XSZ);
    unsigned short* Vtp = (unsigned short*)(ws + 4 * WSZ + 5 * XSZ);  // [B][D][S] direct
    unsigned short* ctx = Xk;  // Xk dead after QKV GEMM

    // 1. fused prep: q/k/v bf16 converts (z=0..2) + 4 weight transposes (z=3..6)
    PrepArgs pargs;
    pargs.csrc[0] = query; pargs.csrc[1] = key; pargs.csrc[2] = value;
    pargs.cdst[0] = Xq; pargs.cdst[1] = Xk; pargs.cdst[2] = Xv;
    pargs.wsrc[0] = Wq; pargs.wsrc[1] = Wk; pargs.wsrc[2] = Wv; pargs.wsrc[3] = Wo;
    pargs.wdst[0] = Wqt; pargs.wdst[1] = Wkt; pargs.wdst[2] = Wvt; pargs.wdst[3] = Wot;
    prep_inputs<<<dim3(32, 32, 7), 256, 0, stream>>>(pargs);

    // 2. Q/K/V projections: m201-faithful 256x256 BK=64 pipeline;
    //    z=2 writes V^T [B][D][S] directly (transpose fused)
    QKVArgs args;
    args.A[0] = Xq; args.A[1] = Xk; args.A[2] = Xv;
    args.Bt[0] = Wqt; args.Bt[1] = Wkt; args.Bt[2] = Wvt;
    args.bias[0] = bq; args.bias[1] = bk; args.bias[2] = bv;
    args.C[0] = Qp; args.C[1] = Kp; args.C[2] = Vtp;
    gemm_qkv<<<dim3(DD / 256, MM / 256, 3), 512, 0, stream>>>(args);

    // 3. flash attention: 512 blocks = 32 heads x 16 q-groups (4 waves x 32 q each)
    flash_attn<<<BB * HH * 16, 256, 0, stream>>>(Qp, Kp, Vtp, ctx);

    // 4. output projection -> fp32: 128x64 tiles, 512 blocks (2/CU)
    gemm_out<<<dim3(DD / 64, MM / 128), 256, 0, stream>>>(ctx, Wot, bo, out);
}